// Round 5
// baseline (199.911 us; speedup 1.0000x reference)
//
#include <hip/hip_runtime.h>

// TT embedding lookup, grouped by (table, i1); each core1 row streamed ONCE,
// contiguously, with nontemporal dwordx4 loads.
// P=(216,216,216), Q=(2,4,2), R=(128,128), tables=2, batch=1024.
// core0: [2,216,256]   (A row:  [Q0=2][R0=128])
// core1: [2,216,65536] (Bm row: [R0=128][S=512], S = q1*128 + r1)
// core2: [2,216,256]   (C row:  [R1=128][Q2=2])
// out:   [2,1024,16]   (flat per lookup: q0*8 + q1*2 + j)
//
// d_ws int layout:
//   [0,432)      group start offsets
//   [432,864)    group counts
//   [864,2912)   sorted lookup ids (counting sort by group)
//   [2912,4960)  per-lookup aux: (i0<<16)|i2
//
// tt_main grid: (432 groups, 2 chunk-slots) x 256 threads (4 waves).
// Wave w streams rows [32w, 32w+32) = contiguous 64 KB; lane owns cols
// {4L..4L+3, 256+4L..+3} (two dwordx4 per row). 8 lookups per pass.
// Stage-2 (C contraction) applied to each wave's r-partial, then 4-way
// combine via LDS.

#define NGROUPS 432
#define NLOOK   2048

typedef float f4 __attribute__((ext_vector_type(4)));

__global__ __launch_bounds__(512) void tt_prep(const int* __restrict__ idx32,
                                               int* __restrict__ w) {
    __shared__ int cnt[NGROUPS];
    __shared__ int wtot[8];
    __shared__ int cursor[NGROUPS];
    const int tid  = threadIdx.x;
    const int lane = tid & 63;
    const int wv   = tid >> 6;

    for (int i = tid; i < NGROUPS; i += 512) cnt[i] = 0;
    __syncthreads();

    // int64-vs-int32 buffer detection (values < 2^31 => odd words zero in LE int64)
    const bool is64 = (idx32[1] == 0) & (idx32[3] == 0) &
                      (idx32[5] == 0) & (idx32[7] == 0);

    int grp[4];
#pragma unroll
    for (int j = 0; j < 4; ++j) {
        const int id = tid + j * 512;
        const unsigned idx = is64 ? (unsigned)((const long long*)idx32)[id]
                                  : (unsigned)idx32[id];
        const unsigned i0  = idx / 46656u;
        const unsigned rem = idx - i0 * 46656u;
        const unsigned i1  = rem / 216u;
        const unsigned i2  = rem - i1 * 216u;
        const int table = id >> 10;
        grp[j] = table * 216 + (int)i1;
        w[2912 + id] = (int)((i0 << 16) | i2);
        atomicAdd(&cnt[grp[j]], 1);
    }
    __syncthreads();

    // two-level exclusive scan: shfl wave-scan + wave-total offsets
    const int v = (tid < NGROUPS) ? cnt[tid] : 0;
    int s = v;
#pragma unroll
    for (int d = 1; d < 64; d <<= 1) {
        const int t = __shfl_up(s, d);
        if (lane >= d) s += t;
    }
    if (lane == 63) wtot[wv] = s;
    __syncthreads();
    int off = 0;
    for (int i = 0; i < wv; ++i) off += wtot[i];
    if (tid < NGROUPS) {
        const int st = s + off - v;        // exclusive prefix
        w[tid]       = st;
        w[432 + tid] = v;
        cursor[tid]  = st;
    }
    __syncthreads();

#pragma unroll
    for (int j = 0; j < 4; ++j) {
        const int id  = tid + j * 512;
        const int pos = atomicAdd(&cursor[grp[j]], 1);
        w[864 + pos] = id;
    }
}

__global__ __launch_bounds__(256) void tt_main(
    const float* __restrict__ c0,
    const float* __restrict__ c1,
    const float* __restrict__ c2,
    const int* __restrict__ w,
    float* __restrict__ out)
{
    const int g  = blockIdx.x;      // group id [0,432)
    const int cs = blockIdx.y;      // chunk slot {0,1}
    const int m = w[432 + g];
    if (m <= cs * 8) return;
    const int s0    = w[g];
    const int table = g / 216;
    const int i1    = g - table * 216;

    const int tid = threadIdx.x;
    const int wv  = tid >> 6;       // wave = r-slice [32*wv, 32*wv+32)
    const int L   = tid & 63;

    __shared__ float A[2048];       // A[l][2*r + q0] interleave (broadcast reads)
    __shared__ float comb[512];     // [wave][l*16 + q0*8 + q1*2 + j]
    __shared__ int s_id[8];
    __shared__ int s_aux[8];

    // wave's contiguous stream: rows [32wv, 32wv+32) x all 512 cols = 64 KB
    const f4* bw = (const f4*)(c1 + (((size_t)(table * 216 + i1)) << 16))
                   + (size_t)(32 * wv) * 128 + L;
    const float* c0t = c0 + (size_t)table * 216 * 256;
    const float* c2t = c2 + (size_t)table * 216 * 256;

    const int r1  = (L & 31) * 4;   // col base within a q1 block (same both chunks)
    const int q1b = L >> 5;

    for (int base = cs * 8; base < m; base += 16) {
        const int cl = min(8, m - base);
        __syncthreads();            // previous pass's LDS reads done
        if (tid < 8) {
            const bool ok = tid < cl;
            const int id  = ok ? w[864 + s0 + base + tid] : 0;
            s_id[tid]  = id;
            s_aux[tid] = ok ? w[2912 + id] : 0;   // pad -> row 0, output gated
        }
        __syncthreads();

        // stage A: coalesced 1 KB global read per l, stride-2 LDS store (free)
#pragma unroll
        for (int l = 0; l < 8; ++l) {
            const float* ar = c0t + (size_t)(s_aux[l] >> 16) * 256;
            A[l * 256 + 2 * (tid & 127) + (tid >> 7)] = ar[tid];
        }
        __syncthreads();

        f4 acc[8][2][2];            // [l][q0][col-chunk]
#pragma unroll
        for (int l = 0; l < 8; ++l)
#pragma unroll
            for (int q = 0; q < 2; ++q) {
                acc[l][q][0] = (f4)0.f;
                acc[l][q][1] = (f4)0.f;
            }

#pragma unroll 4
        for (int rr = 0; rr < 32; ++rr) {
            const f4 b0 = __builtin_nontemporal_load(bw + (size_t)rr * 128);
            const f4 b1 = __builtin_nontemporal_load(bw + (size_t)rr * 128 + 64);
            const int r = 32 * wv + rr;
#pragma unroll
            for (int l = 0; l < 8; ++l) {
                const float2 av = *(const float2*)&A[l * 256 + 2 * r];
                acc[l][0][0] += av.x * b0;
                acc[l][1][0] += av.y * b0;
                acc[l][0][1] += av.x * b1;
                acc[l][1][1] += av.y * b1;
            }
        }

        // stage 2 per wave on its r-partial (linear => valid), butterfly per l
#pragma unroll
        for (int l = 0; l < 8; ++l) {
            const float* crow = c2t + (size_t)(s_aux[l] & 0xffff) * 256;
            const f4 cA = *(const f4*)(crow + 2 * r1);      // C[r1..r1+1][0..1]
            const f4 cB = *(const f4*)(crow + 2 * r1 + 4);  // C[r1+2..r1+3][0..1]
            float p[2][2][2];       // [q0][chunk][j]
#pragma unroll
            for (int q = 0; q < 2; ++q)
#pragma unroll
                for (int c = 0; c < 2; ++c) {
                    const f4 a = acc[l][q][c];
                    p[q][c][0] = a.x*cA.x + a.y*cA.z + a.z*cB.x + a.w*cB.z;
                    p[q][c][1] = a.x*cA.y + a.y*cA.w + a.z*cB.y + a.w*cB.w;
                }
#pragma unroll
            for (int mm = 16; mm >= 1; mm >>= 1) {
#pragma unroll
                for (int q = 0; q < 2; ++q)
#pragma unroll
                    for (int c = 0; c < 2; ++c) {
                        p[q][c][0] += __shfl_xor(p[q][c][0], mm);
                        p[q][c][1] += __shfl_xor(p[q][c][1], mm);
                    }
            }
            if ((L & 31) == 0) {    // lanes 0 and 32 hold q1 = 2*c + q1b sums
#pragma unroll
                for (int q = 0; q < 2; ++q)
#pragma unroll
                    for (int c = 0; c < 2; ++c) {
                        comb[wv * 128 + l * 16 + q * 8 + (2 * c + q1b) * 2 + 0] = p[q][c][0];
                        comb[wv * 128 + l * 16 + q * 8 + (2 * c + q1b) * 2 + 1] = p[q][c][1];
                    }
            }
        }
        __syncthreads();

        // combine 4 wave-partials; out layout = q0*8 + q1*2 + j
        if (tid < 16 * cl) {
            const int l = tid >> 4, k = tid & 15;
            out[(size_t)s_id[l] * 16 + k] =
                comb[l * 16 + k] + comb[128 + l * 16 + k] +
                comb[256 + l * 16 + k] + comb[384 + l * 16 + k];
        }
    }
}

extern "C" void kernel_launch(void* const* d_in, const int* in_sizes, int n_in,
                              void* d_out, int out_size, void* d_ws, size_t ws_size,
                              hipStream_t stream) {
    const int*   idx = (const int*)d_in[0];
    const float* c0  = (const float*)d_in[1];
    const float* c1  = (const float*)d_in[2];
    const float* c2  = (const float*)d_in[3];
    float* out = (float*)d_out;
    int* w = (int*)d_ws;

    tt_prep<<<dim3(1), dim3(512), 0, stream>>>(idx, w);
    tt_main<<<dim3(NGROUPS, 2), dim3(256), 0, stream>>>(c0, c1, c2, w, out);
}

// Round 6
// 193.108 us; speedup vs baseline: 1.0352x; 1.0352x over previous
//
#include <hip/hip_runtime.h>

// TT embedding lookup, grouped by (table, i1); Bm streamed once, cold-HBM
// optimized: max outstanding loads (8 dwordx4/thread issued before any use),
// 3456 blocks, row-block partials combined via global atomicAdd.
// P=(216,216,216), Q=(2,4,2), R=(128,128), tables=2, batch=1024.
// core0: [2,216,256]   (A row:  [Q0=2][R0=128])
// core1: [2,216,65536] (Bm row: [R0=128][S=512], S = q1*128 + r1)
// core2: [2,216,256]   (C row:  [R1=128][Q2=2])
// out:   [2,1024,16]   (flat per lookup: q0*8 + q1*2 + j)
//
// d_ws int layout:
//   [0,432)      group start offsets
//   [432,864)    group counts
//   [864,2912)   sorted lookup ids (counting sort by group)
//   [2912,4960)  per-lookup aux: (i0<<16)|i2
//
// tt_main grid: (432 groups, 8 row-blocks) x 256 threads. Block (g,rb) owns
// rows [16rb,16rb+16) of g's Bm = 32 KB, read as 8 block-contiguous 4 KB
// sweeps. Thread's fixed cols = 4*(t&127) (one q1, fixed r1), rows 2i+(t>>7).
// All m lookups processed in register-tiles of 8 against the SAME b[] regs.

#define NGROUPS 432
#define NLOOK   2048

typedef float f4 __attribute__((ext_vector_type(4)));

__global__ __launch_bounds__(512) void tt_prep(const int* __restrict__ idx32,
                                               int* __restrict__ w) {
    __shared__ int cnt[NGROUPS];
    __shared__ int wtot[8];
    __shared__ int cursor[NGROUPS];
    const int tid  = threadIdx.x;
    const int lane = tid & 63;
    const int wv   = tid >> 6;

    for (int i = tid; i < NGROUPS; i += 512) cnt[i] = 0;
    __syncthreads();

    // int64-vs-int32 buffer detection (values < 2^31 => odd words zero in LE int64)
    const bool is64 = (idx32[1] == 0) & (idx32[3] == 0) &
                      (idx32[5] == 0) & (idx32[7] == 0);

    int grp[4];
#pragma unroll
    for (int j = 0; j < 4; ++j) {
        const int id = tid + j * 512;
        const unsigned idx = is64 ? (unsigned)((const long long*)idx32)[id]
                                  : (unsigned)idx32[id];
        const unsigned i0  = idx / 46656u;
        const unsigned rem = idx - i0 * 46656u;
        const unsigned i1  = rem / 216u;
        const unsigned i2  = rem - i1 * 216u;
        const int table = id >> 10;
        grp[j] = table * 216 + (int)i1;
        w[2912 + id] = (int)((i0 << 16) | i2);
        atomicAdd(&cnt[grp[j]], 1);
    }
    __syncthreads();

    // two-level exclusive scan: shfl wave-scan + wave-total offsets
    const int v = (tid < NGROUPS) ? cnt[tid] : 0;
    int s = v;
#pragma unroll
    for (int d = 1; d < 64; d <<= 1) {
        const int t = __shfl_up(s, d);
        if (lane >= d) s += t;
    }
    if (lane == 63) wtot[wv] = s;
    __syncthreads();
    int off = 0;
    for (int i = 0; i < wv; ++i) off += wtot[i];
    if (tid < NGROUPS) {
        const int st = s + off - v;        // exclusive prefix
        w[tid]       = st;
        w[432 + tid] = v;
        cursor[tid]  = st;
    }
    __syncthreads();

#pragma unroll
    for (int j = 0; j < 4; ++j) {
        const int id  = tid + j * 512;
        const int pos = atomicAdd(&cursor[grp[j]], 1);
        w[864 + pos] = id;
    }
}

__global__ __launch_bounds__(256) void tt_main(
    const float* __restrict__ c0,
    const float* __restrict__ c1,
    const float* __restrict__ c2,
    const int* __restrict__ w,
    float* __restrict__ out)
{
    const int g  = blockIdx.x;      // group id [0,432)
    const int rb = blockIdx.y;      // row-block: rows [16rb, 16rb+16)
    const int m = w[432 + g];
    if (m == 0) return;
    const int s0    = w[g];
    const int table = g / 216;
    const int i1    = g - table * 216;

    const int t      = threadIdx.x;
    const int h      = t >> 7;        // row parity within each 2-row sweep
    const int lane31 = t & 31;
    const int q1     = (t >> 5) & 3;  // this thread's q1 (col block)

    __shared__ float A_s[8][16][2];   // [l][r_local][q0] (wave-broadcast reads)
    __shared__ float comb[8][36];     // [(h*4+q1)][l*4+q0*2+j], padded stride
    __shared__ int s_id[8];
    __shared__ int s_aux[8];

    // Issue ALL 8 dwordx4 loads up front: block reads 8 contiguous 4 KB
    // sweeps (rows 2i, 2i+1); thread's cols = 4*(t&127), row = 2i + h.
    const f4* bp = (const f4*)(c1 + (((size_t)(table * 216 + i1)) << 16))
                   + (size_t)rb * 2048 + t;
    f4 b[8];
#pragma unroll
    for (int i = 0; i < 8; ++i)
        b[i] = bp[i * 256];

    const float* c0t = c0 + (size_t)table * 216 * 256;
    const float* c2t = c2 + (size_t)table * 216 * 256;
    const int r1 = 4 * lane31;        // col within q1 block

    for (int base = 0; base < m; base += 8) {
        const int cl = min(8, m - base);
        if (base) __syncthreads();    // protect s_* rewrite vs prior tile
        if (t < 8) {
            const bool ok = t < cl;
            const int id  = ok ? w[864 + s0 + base + t] : 0;
            s_id[t]  = id;
            s_aux[t] = ok ? w[2912 + id] : 0;   // pad -> row 0, output gated
        }
        __syncthreads();

        // stage this row-block's A slice: 8l x 16r x 2q0 = 256 floats
        {
            const int l = t >> 5, e = t & 31;
            const int rl = e >> 1, q0 = e & 1;
            A_s[l][rl][q0] =
                c0t[(size_t)(s_aux[l] >> 16) * 256 + q0 * 128 + rb * 16 + rl];
        }
        __syncthreads();

        f4 wacc[8][2];                // [l][q0]
#pragma unroll
        for (int l = 0; l < 8; ++l) { wacc[l][0] = (f4)0.f; wacc[l][1] = (f4)0.f; }

#pragma unroll
        for (int i = 0; i < 8; ++i) {
            const int rl = 2 * i + h;
#pragma unroll
            for (int l = 0; l < 8; ++l) {
                wacc[l][0] += A_s[l][rl][0] * b[i];
                wacc[l][1] += A_s[l][rl][1] * b[i];
            }
        }

        // per-l: C contraction on this r-slice partial (linear => valid),
        // 32-lane butterfly, one writer per (h,q1)
#pragma unroll
        for (int l = 0; l < 8; ++l) {
            if (l < cl) {
                const float* crow =
                    c2t + (size_t)(s_aux[l] & 0xffff) * 256 + 2 * r1;
                const f4 cA = *(const f4*)crow;        // C[r1..r1+1][0..1]
                const f4 cB = *(const f4*)(crow + 4);  // C[r1+2..r1+3][0..1]
                float p00 = wacc[l][0].x*cA.x + wacc[l][0].y*cA.z + wacc[l][0].z*cB.x + wacc[l][0].w*cB.z;
                float p01 = wacc[l][0].x*cA.y + wacc[l][0].y*cA.w + wacc[l][0].z*cB.y + wacc[l][0].w*cB.w;
                float p10 = wacc[l][1].x*cA.x + wacc[l][1].y*cA.z + wacc[l][1].z*cB.x + wacc[l][1].w*cB.z;
                float p11 = wacc[l][1].x*cA.y + wacc[l][1].y*cA.w + wacc[l][1].z*cB.y + wacc[l][1].w*cB.w;
#pragma unroll
                for (int mm = 16; mm >= 1; mm >>= 1) {
                    p00 += __shfl_xor(p00, mm);
                    p01 += __shfl_xor(p01, mm);
                    p10 += __shfl_xor(p10, mm);
                    p11 += __shfl_xor(p11, mm);
                }
                if (lane31 == 0) {
                    float* cb = &comb[h * 4 + q1][l * 4];
                    cb[0] = p00; cb[1] = p01; cb[2] = p10; cb[3] = p11;
                }
            }
        }
        __syncthreads();

        // combine h-halves, atomically add this row-block's contribution
        if (t < 16 * cl) {
            const int l = t >> 4, k = t & 15;          // k = q0*8 + q1*2 + j
            const int q0 = k >> 3, qq = (k >> 1) & 3, j = k & 1;
            const float v = comb[qq][l * 4 + q0 * 2 + j] +
                            comb[4 + qq][l * 4 + q0 * 2 + j];
            atomicAdd(&out[(size_t)s_id[l] * 16 + k], v);
        }
    }
}

extern "C" void kernel_launch(void* const* d_in, const int* in_sizes, int n_in,
                              void* d_out, int out_size, void* d_ws, size_t ws_size,
                              hipStream_t stream) {
    const int*   idx = (const int*)d_in[0];
    const float* c0  = (const float*)d_in[1];
    const float* c1  = (const float*)d_in[2];
    const float* c2  = (const float*)d_in[3];
    float* out = (float*)d_out;
    int* w = (int*)d_ws;

    hipMemsetAsync(out, 0, (size_t)out_size * sizeof(float), stream);
    tt_prep<<<dim3(1), dim3(512), 0, stream>>>(idx, w);
    tt_main<<<dim3(NGROUPS, 8), dim3(256), 0, stream>>>(c0, c1, c2, w, out);
}

// Round 8
// 186.664 us; speedup vs baseline: 1.0710x; 1.0345x over previous
//
#include <hip/hip_runtime.h>

// TT embedding lookup, grouped by (table, i1) so each core1 row is read ~once.
// R8 = R4 structure (best measured: ~53 us) + nontemporal Bm stream +
// C-row register prefetch (epilogue has no global dependency).
// P=(216,216,216), Q=(2,4,2), R=(128,128), tables=2, batch=1024.
// core0: [2,216,256]   (A row:  [Q0=2][R0=128])
// core1: [2,216,65536] (Bm row: [R0=128][S=512], S = q1*128 + r1)
// core2: [2,216,256]   (C row:  [R1=128][Q2=2])
// out:   [2,1024,16]   (flat per lookup: q0*8 + q1*2 + j)
//
// d_ws int layout:
//   [0,432)      group start offsets
//   [432,864)    group counts
//   [864,2912)   sorted lookup ids (counting sort by group)
//   [2912,4960)  per-lookup aux: (i0<<16)|i2
//
// tt_main grid: (432 groups, 4 s-quarters, 2 chunk-slots) x 128 threads
// (2 waves = r-halves). Lane owns 2 columns (float2): acc[8][2] = 32 VGPRs,
// C prefetch adds 32 -> ~110 total, 4 waves/SIMD.

#define NGROUPS 432
#define NLOOK   2048

typedef float f4 __attribute__((ext_vector_type(4)));
typedef float f2 __attribute__((ext_vector_type(2)));

__global__ __launch_bounds__(512) void tt_prep(const int* __restrict__ idx32,
                                               int* __restrict__ w) {
    __shared__ int cnt[NGROUPS];
    __shared__ int wtot[8];
    __shared__ int cursor[NGROUPS];
    const int tid  = threadIdx.x;
    const int lane = tid & 63;
    const int wv   = tid >> 6;

    for (int i = tid; i < NGROUPS; i += 512) cnt[i] = 0;
    __syncthreads();

    // int64-vs-int32 buffer detection (values < 2^31 => odd words zero in LE int64)
    const bool is64 = (idx32[1] == 0) & (idx32[3] == 0) &
                      (idx32[5] == 0) & (idx32[7] == 0);

    int grp[4];
#pragma unroll
    for (int j = 0; j < 4; ++j) {
        const int id = tid + j * 512;
        const unsigned idx = is64 ? (unsigned)((const long long*)idx32)[id]
                                  : (unsigned)idx32[id];
        const unsigned i0  = idx / 46656u;
        const unsigned rem = idx - i0 * 46656u;
        const unsigned i1  = rem / 216u;
        const unsigned i2  = rem - i1 * 216u;
        const int table = id >> 10;
        grp[j] = table * 216 + (int)i1;
        w[2912 + id] = (int)((i0 << 16) | i2);
        atomicAdd(&cnt[grp[j]], 1);
    }
    __syncthreads();

    // two-level exclusive scan: shfl wave-scan + wave-total offsets
    const int v = (tid < NGROUPS) ? cnt[tid] : 0;
    int s = v;
#pragma unroll
    for (int d = 1; d < 64; d <<= 1) {
        const int t = __shfl_up(s, d);
        if (lane >= d) s += t;
    }
    if (lane == 63) wtot[wv] = s;
    __syncthreads();
    int off = 0;
    for (int i = 0; i < wv; ++i) off += wtot[i];
    if (tid < NGROUPS) {
        const int st = s + off - v;        // exclusive prefix
        w[tid]       = st;
        w[432 + tid] = v;
        cursor[tid]  = st;
    }
    __syncthreads();

#pragma unroll
    for (int j = 0; j < 4; ++j) {
        const int id  = tid + j * 512;
        const int pos = atomicAdd(&cursor[grp[j]], 1);
        w[864 + pos] = id;
    }
}

__global__ __launch_bounds__(128) void tt_main(
    const float* __restrict__ c0,
    const float* __restrict__ c1,
    const float* __restrict__ c2,
    const int* __restrict__ w,
    float* __restrict__ out)
{
    const int g  = blockIdx.x;      // group id [0,432)
    const int q  = blockIdx.y;      // s-quarter {0..3} == q1
    const int cs = blockIdx.z;      // chunk slot {0,1}
    const int m = w[432 + g];
    if (m <= cs * 8) return;
    const int s0    = w[g];
    const int table = g / 216;
    const int i1    = g - table * 216;

    const int tid = threadIdx.x;
    const int rh  = tid >> 6;       // r-half: wave0 r<64, wave1 r>=64
    const int tl  = tid & 63;

    // 8 KB LDS, dual-purpose: A staging ([l][2r+q0] interleave) during the
    // FMA loop; wave1's partial accumulators during the r-split combine.
    __shared__ float lds[2048];
    f2* lds2 = (f2*)lds;
    __shared__ int s_id[8];
    __shared__ int s_aux[8];

    // lane owns cols s = 128*q + 2*tl (+1); f2 index into row: r*256 + 64q + tl
    const f2* b2 = (const f2*)(c1 + (((size_t)(table * 216 + i1)) << 16))
                   + (size_t)rh * 64 * 256 + (q * 64 + tl);
    const float* c0t = c0 + (size_t)table * 216 * 256;
    const float* c2t = c2 + (size_t)table * 216 * 256;

    for (int base = cs * 8; base < m; base += 16) {
        const int cl = min(8, m - base);
        __syncthreads();            // previous pass's LDS reads done
        if (tid < 8) {
            const bool ok = tid < cl;
            const int id  = ok ? w[864 + s0 + base + tid] : 0;
            s_id[tid]  = id;
            s_aux[tid] = ok ? w[2912 + id] : 0;   // pad -> row 0 (in-bounds, output gated)
        }
        __syncthreads();

        // Prefetch per-lookup C rows into registers (lane's r1 pair = 2*tl,
        // 2*tl+1 -> 4 floats at crow[4*tl]); pads load row 0 harmlessly.
        f4 cv[8];
#pragma unroll
        for (int l = 0; l < 8; ++l)
            cv[l] = *(const f4*)(c2t + (size_t)(s_aux[l] & 0xffff) * 256 + 4 * tl);

        // stage A: coalesced global read, transposed LDS store (stride-2 = free)
#pragma unroll
        for (int l = 0; l < 8; ++l) {
            const float* ar = c0t + (size_t)(s_aux[l] >> 16) * 256;
#pragma unroll
            for (int k = 0; k < 2; ++k) {
                const int e = tid + 128 * k;              // e = q0*128 + r
                lds[l * 256 + 2 * (e & 127) + (e >> 7)] = ar[e];
            }
        }
        __syncthreads();

        f2 acc[8][2];
#pragma unroll
        for (int l = 0; l < 8; ++l) {
            acc[l][0] = (f2)0.f;
            acc[l][1] = (f2)0.f;
        }

#pragma unroll 8
        for (int rr = 0; rr < 64; ++rr) {
            const f2 bv = __builtin_nontemporal_load(b2 + (size_t)rr * 256);
            const int r = rh * 64 + rr;
#pragma unroll
            for (int l = 0; l < 8; ++l) {
                const f2 av = lds2[l * 128 + r];   // (A[0][r], A[1][r]) broadcast
                acc[l][0] += av.x * bv;
                acc[l][1] += av.y * bv;
            }
        }

        // r-split combine: wave1 -> LDS (overwrites A region), wave0 adds.
        __syncthreads();
        if (rh == 1) {
#pragma unroll
            for (int l = 0; l < 8; ++l) {
                lds2[(l * 2 + 0) * 64 + tl] = acc[l][0];
                lds2[(l * 2 + 1) * 64 + tl] = acc[l][1];
            }
        }
        __syncthreads();

        if (rh == 0) {
#pragma unroll
            for (int l = 0; l < 8; ++l) {
                const f2 t0 = lds2[(l * 2 + 0) * 64 + tl];
                const f2 t1 = lds2[(l * 2 + 1) * 64 + tl];
                const float a0x = acc[l][0].x + t0.x, a0y = acc[l][0].y + t0.y;
                const float a1x = acc[l][1].x + t1.x, a1y = acc[l][1].y + t1.y;
                if (l < cl) {
                    // C[r1][j] pair already in cv[l] = (C[2tl][0],C[2tl][1],C[2tl+1][0],C[2tl+1][1])
                    float p00 = a0x * cv[l].x + a0y * cv[l].z;
                    float p01 = a0x * cv[l].y + a0y * cv[l].w;
                    float p10 = a1x * cv[l].x + a1y * cv[l].z;
                    float p11 = a1x * cv[l].y + a1y * cv[l].w;
#pragma unroll
                    for (int mm = 32; mm >= 1; mm >>= 1) {
                        p00 += __shfl_xor(p00, mm);
                        p01 += __shfl_xor(p01, mm);
                        p10 += __shfl_xor(p10, mm);
                        p11 += __shfl_xor(p11, mm);
                    }
                    if (tl == 0) {
                        float* o = out + (size_t)s_id[l] * 16;
                        o[q * 2 + 0]     = p00;   // (q0=0, q1=q, j)
                        o[q * 2 + 1]     = p01;
                        o[8 + q * 2 + 0] = p10;   // q0=1
                        o[8 + q * 2 + 1] = p11;
                    }
                }
            }
        }
    }
}

extern "C" void kernel_launch(void* const* d_in, const int* in_sizes, int n_in,
                              void* d_out, int out_size, void* d_ws, size_t ws_size,
                              hipStream_t stream) {
    const int*   idx = (const int*)d_in[0];
    const float* c0  = (const float*)d_in[1];
    const float* c1  = (const float*)d_in[2];
    const float* c2  = (const float*)d_in[3];
    float* out = (float*)d_out;
    int* w = (int*)d_ws;

    tt_prep<<<dim3(1), dim3(512), 0, stream>>>(idx, w);
    tt_main<<<dim3(NGROUPS, 4, 2), dim3(128), 0, stream>>>(c0, c1, c2, w, out);
}